// Round 8
// baseline (321.154 us; speedup 1.0000x reference)
//
#include <hip/hip_runtime.h>
#include <math.h>

// Problem constants
#define NF 5
#define NB 8
#define NC 64
#define HW 16384
#define NK 320               // NF*NC
#define EN_FLOATS (NB*NC*8)  // per (b,c): E0..E3, N0..N3

#define WIN1 256             // k1 spatial window (floats)
#define NT  40               // k-tiles of 8 rows (320 total)

__device__ __forceinline__ float redsum64(float v){
#pragma unroll
    for (int m = 1; m < 64; m <<= 1) v += __shfl_xor(v, m, 64);
    return v;
}

// ---------------- k0: pack origin_w [64][320] -> Wp[slice=c>>3][k=320][8] ----------------
// k1's wave wv owns output channels 8wv..8wv+7; per k its 8 weights are the
// contiguous 8 floats Wp[wv][k][0..7] -> 2 uniform s_load_dwordx4 per k,
// each reused by 32 FMAs (r6's best SMEM:FMA ratio, 4x fewer SMEM than r7).
__global__ void k0_wp(const float* __restrict__ W, float* __restrict__ Wp){
    int idx = blockIdx.x*256 + threadIdx.x;     // 80 blocks: 20480 = NC*NK
    if (idx < NC*NK){
        int c = idx / NK;
        int k = idx - c*NK;
        Wp[(size_t)(c>>3)*(NK*8) + k*8 + (c&7)] = W[idx];
    }
}

// ---------------- k1: GEMM + E/N, full-dedup ingest design ----------------
// r4/r6/r7 post-mortem: per-CU vector-memory ingest saturates at ~24-25
// GB/s/CU (= m13's 6.3 TB/s / 256 CU) in every staged variant; cgrp siblings
// made each X byte enter 2-4 CUs. Fix: block owns ALL 64 output channels for
// its window -> every input byte enters exactly ONE CU once for the GEMM.
//   Block = 512 thr = 8 waves; wave wv owns channels 8wv..+7; lane owns 4
//   consecutive floats of the 256-float window. Grid 512 = 8b x 64win, 2
//   blocks/CU, 16 waves/CU. LDS 16 KB = two [8][256] tiles, 2-deep reg-staged
//   pipeline (r6-proven): iter kt ds_writes T(kt+1), issues loads for T(kt+3).
//   Stage: thread t loads ONE float4 (row t>>6, col (t&63)*4) = 1 KB/row burst.
//   Inner: per k: 1 ds_read_b128 (same row broadcast to all 8 waves) + 2
//   s_load_dwordx4 + 32 FMAs.
// Phase B (E/N): wave re-reads its 8 channels' 5 frame-rows in the window
// (L2-hot: just streamed by this block's GEMM), dots vs accs, shfl butterfly,
// lane0 atomics into EN.
__global__ __launch_bounds__(512, 2) void k1_fused(
    const float* __restrict__ inp, const float* __restrict__ Wp,
    const float* __restrict__ bias, float* __restrict__ EN)
{
    __shared__ float S[2*8*WIN1];   // 16 KB: two 8x256 tiles

    const int tid = threadIdx.x;
    const int l    = tid & 63;                                  // lane
    const int wv   = __builtin_amdgcn_readfirstlane(tid >> 6);  // wave 0..7
    const int blk  = blockIdx.x;
    const int b    = blk >> 6;
    const int s0   = (blk & 63) << 8;        // 256-float window
    const int cf   = wv << 3;                // first of this wave's 8 channels
    const int srow = tid >> 6;               // staging row 0..7
    const int scol = (tid & 63) << 2;        // staging col (float)

    // accumulators: channel j (0..7), s = s0 + 4l
    float4 A[8];
    {
        float4 b0 = *reinterpret_cast<const float4*>(bias + cf);
        float4 b1 = *reinterpret_cast<const float4*>(bias + cf + 4);
        A[0] = make_float4(b0.x,b0.x,b0.x,b0.x);
        A[1] = make_float4(b0.y,b0.y,b0.y,b0.y);
        A[2] = make_float4(b0.z,b0.z,b0.z,b0.z);
        A[3] = make_float4(b0.w,b0.w,b0.w,b0.w);
        A[4] = make_float4(b1.x,b1.x,b1.x,b1.x);
        A[5] = make_float4(b1.y,b1.y,b1.y,b1.y);
        A[6] = make_float4(b1.z,b1.z,b1.z,b1.z);
        A[7] = make_float4(b1.w,b1.w,b1.w,b1.w);
    }

    const float* Wk = Wp + (size_t)wv*(NK*8);    // uniform slice base -> s_load

#define XROW(K) (inp + ((size_t)(((K)>>6)*NB + b)*NC + ((K)&63))*HW + s0 + scol)
#define LOADSET(R, KT)  { R = *reinterpret_cast<const float4*>(XROW((KT)*8 + srow)); }
#define WRITESET(R, BUF){ *reinterpret_cast<float4*>(S + (BUF)*(8*WIN1) + srow*WIN1 + scol) = R; }

    float4 rA, rB;
    // prologue: T0->A, T1->B, write T0, refill A with T2
    LOADSET(rA, 0)
    LOADSET(rB, 1)
    WRITESET(rA, 0)                 // waits only A's load (counted vmcnt)
    LOADSET(rA, 2)
    __syncthreads();

#pragma unroll 2
    for (int kt=0; kt<NT; ++kt){
        if (kt & 1){
            if (kt < NT-1) WRITESET(rA, (kt+1)&1)
            if (kt < NT-3) LOADSET (rA, kt+3)
        } else {
            if (kt < NT-1) WRITESET(rB, (kt+1)&1)
            if (kt < NT-3) LOADSET (rB, kt+3)
        }
        const float* X  = S + (kt&1)*(8*WIN1) + (l<<2);
        const float* wt = Wk + kt*64;        // 8 k x 8 ch floats, uniform
#pragma unroll
        for (int k=0; k<8; ++k){
            float4 xv = *reinterpret_cast<const float4*>(X + k*WIN1);
            float4 w0 = *reinterpret_cast<const float4*>(wt + k*8);      // s_load_dwordx4
            float4 w1 = *reinterpret_cast<const float4*>(wt + k*8 + 4);  // s_load_dwordx4
            A[0].x = fmaf(w0.x, xv.x, A[0].x); A[0].y = fmaf(w0.x, xv.y, A[0].y);
            A[0].z = fmaf(w0.x, xv.z, A[0].z); A[0].w = fmaf(w0.x, xv.w, A[0].w);
            A[1].x = fmaf(w0.y, xv.x, A[1].x); A[1].y = fmaf(w0.y, xv.y, A[1].y);
            A[1].z = fmaf(w0.y, xv.z, A[1].z); A[1].w = fmaf(w0.y, xv.w, A[1].w);
            A[2].x = fmaf(w0.z, xv.x, A[2].x); A[2].y = fmaf(w0.z, xv.y, A[2].y);
            A[2].z = fmaf(w0.z, xv.z, A[2].z); A[2].w = fmaf(w0.z, xv.w, A[2].w);
            A[3].x = fmaf(w0.w, xv.x, A[3].x); A[3].y = fmaf(w0.w, xv.y, A[3].y);
            A[3].z = fmaf(w0.w, xv.z, A[3].z); A[3].w = fmaf(w0.w, xv.w, A[3].w);
            A[4].x = fmaf(w1.x, xv.x, A[4].x); A[4].y = fmaf(w1.x, xv.y, A[4].y);
            A[4].z = fmaf(w1.x, xv.z, A[4].z); A[4].w = fmaf(w1.x, xv.w, A[4].w);
            A[5].x = fmaf(w1.y, xv.x, A[5].x); A[5].y = fmaf(w1.y, xv.y, A[5].y);
            A[5].z = fmaf(w1.y, xv.z, A[5].z); A[5].w = fmaf(w1.y, xv.w, A[5].w);
            A[6].x = fmaf(w1.z, xv.x, A[6].x); A[6].y = fmaf(w1.z, xv.y, A[6].y);
            A[6].z = fmaf(w1.z, xv.z, A[6].z); A[6].w = fmaf(w1.z, xv.w, A[6].w);
            A[7].x = fmaf(w1.w, xv.x, A[7].x); A[7].y = fmaf(w1.w, xv.y, A[7].y);
            A[7].z = fmaf(w1.w, xv.z, A[7].z); A[7].w = fmaf(w1.w, xv.w, A[7].w);
        }
        __syncthreads();
    }
#undef LOADSET
#undef WRITESET
#undef XROW

    // ---- phase B: E/N for this wave's 8 channels over the 256-s window ----
#pragma unroll
    for (int j=0; j<8; ++j){
        const float* p4 = inp + ((size_t)(4*NB + b)*NC + (cf+j))*HW + s0 + (l<<2);
        float4 x4 = *reinterpret_cast<const float4*>(p4);
#pragma unroll
        for (int i=0; i<4; ++i){
            const float* pi = inp + ((size_t)(i*NB + b)*NC + (cf+j))*HW + s0 + (l<<2);
            float4 xi = *reinterpret_cast<const float4*>(pi);
            float dx = x4.x - xi.x, dy = x4.y - xi.y;
            float dz = x4.z - xi.z, dw = x4.w - xi.w;
            float n = fmaf(dx,dx, fmaf(dy,dy, fmaf(dz,dz, dw*dw)));
            float e = fmaf(A[j].x,dx, fmaf(A[j].y,dy, fmaf(A[j].z,dz, A[j].w*dw)));
            e = redsum64(e); n = redsum64(n);
            if (l == 0){
                float* p = EN + ((size_t)b*NC + cf + j)*8;
                atomicAdd(p + i,     e);
                atomicAdd(p + 4 + i, n);
            }
        }
    }
}

// ---------------- k3: finalize coefs (inlined k2) + y = alpha . inp ----------------
// Full-dedup: grid 512 = (b:8) x (win:64 of 256 floats); every input byte is
// read by exactly one block. 256 thr = 4 row-groups x 64 lanes; per row the
// 64 lanes read 1 KB contiguous; 80 rows/group, unroll 8 -> 8 loads in
// flight. LDS 4-way reduce, ONE direct float4 store, no atomics.
__global__ __launch_bounds__(256, 8) void k3_out(const float* __restrict__ inp,
        const float* __restrict__ EN, const float* __restrict__ out_w,
        const float* __restrict__ out_b, float* __restrict__ y)
{
    __shared__ float  Al[NK];
    __shared__ float4 P[256];
    const int tid = threadIdx.x;
    const int blk = blockIdx.x;
    const int b   = blk >> 6;            // 0..7
    const int s0  = (blk & 63) << 8;     // 256-float window
    const int sg  = tid & 63;            // float4 slot
    const int rg  = tid >> 6;            // 0..3: 80-row group

    if (tid < 64){          // inline k2: coefs for channel c = tid
        const int c = tid;
        const float* e = EN + ((size_t)b*NC + c)*8;
        float w1 = out_w[c], w2 = out_w[NC + c];
        float csum = 0.f;
#pragma unroll
        for (int i=0; i<4; ++i){
            float nc = fmaxf(sqrtf(e[4+i]), 1e-12f);
            float coef = e[i] / (nc*nc);
            Al[i*NC + c] = -w1*coef;
            csum += coef;
        }
        Al[4*NC + c] = w1*csum + w2;
    }
    __syncthreads();

    float4 acc = make_float4(0.f,0.f,0.f,0.f);
    const int rbase = rg*80;
#pragma unroll 8
    for (int j=0; j<80; ++j){
        int r = rbase + j;
        const float* p = inp + ((size_t)((r>>6)*NB + b)*NC + (r&63))*HW + s0 + (sg<<2);
        float  w  = Al[r];                                   // wave-uniform broadcast
        float4 xv = *reinterpret_cast<const float4*>(p);
        acc.x = fmaf(w, xv.x, acc.x); acc.y = fmaf(w, xv.y, acc.y);
        acc.z = fmaf(w, xv.z, acc.z); acc.w = fmaf(w, xv.w, acc.w);
    }
    P[tid] = acc;
    __syncthreads();
    if (tid < 64){
        float4 r0 = P[tid], r1 = P[tid+64], r2 = P[tid+128], r3 = P[tid+192];
        float bb = out_b[0];
        float4 o = make_float4(r0.x+r1.x+r2.x+r3.x + bb,
                               r0.y+r1.y+r2.y+r3.y + bb,
                               r0.z+r1.z+r2.z+r3.z + bb,
                               r0.w+r1.w+r2.w+r3.w + bb);
        *reinterpret_cast<float4*>(y + (size_t)b*HW + s0 + (tid<<2)) = o;
    }
}

extern "C" void kernel_launch(void* const* d_in, const int* in_sizes, int n_in,
                              void* d_out, int out_size, void* d_ws, size_t ws_size,
                              hipStream_t stream)
{
    const float* inp      = (const float*)d_in[0];
    const float* origin_w = (const float*)d_in[1];
    const float* origin_b = (const float*)d_in[2];
    const float* out_w    = (const float*)d_in[3];
    const float* out_b    = (const float*)d_in[4];
    float* y  = (float*)d_out;
    float* ws = (float*)d_ws;

    float* EN = ws;                   // 4096 floats
    float* Wp = ws + EN_FLOATS;       // 20480 floats

    hipMemsetAsync(EN, 0, EN_FLOATS*sizeof(float), stream);
    k0_wp   <<<80,  256, 0, stream>>>(origin_w, Wp);
    k1_fused<<<512, 512, 0, stream>>>(inp, Wp, origin_b, EN);
    k3_out  <<<512, 256, 0, stream>>>(inp, EN, out_w, out_b, y);
}